// Round 13
// baseline (86.820 us; speedup 1.0000x reference)
//
#include <hip/hip_runtime.h>
#include <hip/hip_bf16.h>
#include <hip/hip_cooperative_groups.h>

namespace cg = cooperative_groups;

#define BB 64
#define NN 512
#define FF 64
#define KK 16
#define GG 32
#define TOPKN 4

typedef __attribute__((ext_vector_type(8))) __bf16 bf16x8;
typedef __attribute__((ext_vector_type(4))) float f32x4;

// workspace layout (float offsets)
#define ROUTET_OFF 0                               // fp32 [b][k][i]  = 524288 f
#define E1CB_OFF   (BB*NN*KK)                      // bf16 [e,k,i,d]  = 262144 f
#define E2SB_OFF   (E1CB_OFF + (2*KK*NN*GG)/2)     // bf16 1024x512   = 262144 f
#define XT_OFF     (E2SB_OFF + (2*KK*GG*NN)/2)     // bf16 [b][f][j]  = 1048576 f
#define MT_OFF     (XT_OFF + (BB*FF*NN)/2)         // bf16 [b][f][ked]= 2097152 f

// ---------------------------------------------------------------------------
// Fused prep kernel, grid-sectioned (identical to R12)
// ---------------------------------------------------------------------------
__global__ __launch_bounds__(256)
void prep_kernel(const float* __restrict__ x, const float* __restrict__ E1,
                 const float* __restrict__ E2, const float* __restrict__ rw,
                 const float* __restrict__ rb, const int* __restrict__ bias,
                 const float* __restrict__ lq1, const float* __restrict__ lk1,
                 const float* __restrict__ lq2, const float* __restrict__ lk2,
                 float* __restrict__ routeT, float* __restrict__ topk_out,
                 __hip_bfloat16* __restrict__ E1cb,
                 __hip_bfloat16* __restrict__ E2sb,
                 __hip_bfloat16* __restrict__ xT)
{
    __shared__ float sm[4224];
    const int B = blockIdx.x;
    const int t = threadIdx.x;

    if (B < 512) {
        // ---- xpose ----
        const int b = B >> 3;
        const int j0 = (B & 7) * 64;
        const float* xb = x + (long)b * NN * FF;
        __hip_bfloat16* xo = xT + (long)b * FF * NN;
        const float4* src = (const float4*)(xb + (long)j0 * FF);
#pragma unroll
        for (int q = 0; q < 4; ++q) {
            int idx = t + q * 256;
            float4 v = src[idx];
            int j = idx >> 4;
            int f = (idx & 15) * 4;
            sm[j * 65 + f + 0] = v.x;
            sm[j * 65 + f + 1] = v.y;
            sm[j * 65 + f + 2] = v.z;
            sm[j * 65 + f + 3] = v.w;
        }
        __syncthreads();
#pragma unroll
        for (int q = 0; q < 16; ++q) {
            int idx = t + q * 256;
            int f = idx >> 6, j = idx & 63;
            xo[(long)f * NN + j0 + j] = __float2bfloat16(sm[j * 65 + f]);
        }
    } else if (B < 1536) {
        // ---- e2 softmax ----
        const long base = (long)(B - 512) * NN;
        float v0 = E2[base + t], v1 = E2[base + t + 256];
        float m = fmaxf(v0, v1);
#pragma unroll
        for (int s = 32; s >= 1; s >>= 1) m = fmaxf(m, __shfl_xor(m, s));
        if ((t & 63) == 0) sm[t >> 6] = m;
        __syncthreads();
        m = fmaxf(fmaxf(sm[0], sm[1]), fmaxf(sm[2], sm[3]));
        float e0 = expf(v0 - m), e1 = expf(v1 - m);
        float s2 = e0 + e1;
#pragma unroll
        for (int s = 32; s >= 1; s >>= 1) s2 += __shfl_xor(s2, s);
        __syncthreads();
        if ((t & 63) == 0) sm[t >> 6] = s2;
        __syncthreads();
        s2 = sm[0] + sm[1] + sm[2] + sm[3];
        E2sb[base + t] = __float2bfloat16(e0 / s2);
        E2sb[base + t + 256] = __float2bfloat16(e1 / s2);
    } else if (B < 2048) {
        // ---- e1 softmax * coef ----
        const long base = (long)(B - 1536) * 32;
        const int e = (int)(base >> 13);
        float coef = 1.0f;
        if (e) {
            float l1 = 0.f, l2 = 0.f;
#pragma unroll
            for (int i = 0; i < 64; ++i) {
                l1 = fmaf(lq1[i], lk1[i], l1);
                l2 = fmaf(lq2[i], lk2[i], l2);
            }
            const float lambda_init = 0.3555090675909692f;
            coef = -(expf(l1) - expf(l2) + lambda_init);
        }
        const int l = t & 31;
#pragma unroll
        for (int it = 0; it < 4; ++it) {
            const long row = base + it * 8 + (t >> 5);
            float val = E1[row * GG + l];
            float m = val;
#pragma unroll
            for (int s = 16; s >= 1; s >>= 1) m = fmaxf(m, __shfl_xor(m, s, 32));
            float ex = expf(val - m);
            float sum = ex;
#pragma unroll
            for (int s = 16; s >= 1; s >>= 1) sum += __shfl_xor(sum, s, 32);
            E1cb[row * GG + l] = __float2bfloat16(coef * (ex / sum));
        }
    } else {
        // ---- router: 2 half-threads per row; ordering by raw fp64 logit ----
        float* rwl = sm;
        float* rbl = sm + 1024;
        if (t < KK) rbl[t] = rb[t];
        for (int i = t; i < KK * FF; i += 256) rwl[i] = rw[i];
        __syncthreads();

        const int wv = t >> 6, ln = t & 63;
        const int khalf = ln >> 5;
        const long row = (long)(B - 2048) * 128 + wv * 32 + (ln & 31);

        float xr[FF];
        const float4* xrp = (const float4*)(x + row * FF);
#pragma unroll
        for (int c = 0; c < 16; ++c) {
            float4 v = xrp[c];
            xr[c * 4 + 0] = v.x; xr[c * 4 + 1] = v.y;
            xr[c * 4 + 2] = v.z; xr[c * 4 + 3] = v.w;
        }

        const int kb = khalf * 8;
        double mine[8];
#pragma unroll
        for (int kk = 0; kk < 8; ++kk) {
            double s = (double)rbl[kb + kk];
#pragma unroll
            for (int f = 0; f < FF; ++f)
                s += (double)rwl[(kb + kk) * FF + f] * (double)xr[f];
            mine[kk] = s;
        }
        double other[8];
#pragma unroll
        for (int i = 0; i < 8; ++i) other[i] = __shfl_xor(mine[i], 32);

        if (khalf == 0) {
            double sv[KK];
#pragma unroll
            for (int i = 0; i < 8; ++i) { sv[i] = mine[i]; sv[8 + i] = other[i]; }

            int idx4[TOPKN];
            double sval[TOPKN];
#pragma unroll
            for (int tt = 0; tt < TOPKN; ++tt) {
                double m = -1e300; int mi = 0;
#pragma unroll
                for (int k = 0; k < KK; ++k)
                    if (sv[k] > m) { m = sv[k]; mi = k; }
                idx4[tt] = mi;
                sval[tt] = m;
                sv[mi] = -1e300;
            }
            float sig4[TOPKN];
            float ssum = 0.f;
#pragma unroll
            for (int tt = 0; tt < TOPKN; ++tt) {
                sig4[tt] = 1.0f / (1.0f + expf(-(float)sval[tt]));
                ssum += sig4[tt];
            }
            float rv[KK];
#pragma unroll
            for (int k = 0; k < KK; ++k) rv[k] = 0.f;
#pragma unroll
            for (int tt = 0; tt < TOPKN; ++tt)
                rv[idx4[tt]] = sig4[tt] / ssum;

            const int b = (int)(row >> 9);
            const int n = (int)(row & 511);
#pragma unroll
            for (int k = 0; k < KK; ++k)
                routeT[((long)b * KK + k) * NN + n] = rv[k];
            float4 ti = make_float4((float)idx4[0], (float)idx4[1],
                                    (float)idx4[2], (float)idx4[3]);
            *(float4*)(topk_out + row * TOPKN) = ti;
        }
    }
}

// ---------------------------------------------------------------------------
// Cooperative A+B kernel: grid 256 x 256thr (phaseA's exact proven shape).
// Section A: verbatim R10/R12 phaseA. grid.sync. Section B: 256 blocks, each
// covers 128 i-rows (two 16-row sub-tiles per wave) sharing ONE Mt staging
// stream: halves B's L2 traffic, each ds_read feeds 2 MFMAs.
// ---------------------------------------------------------------------------
__global__ __launch_bounds__(256, 1)
void phaseAB_coop(const __hip_bfloat16* __restrict__ E2sb,
                  const __hip_bfloat16* __restrict__ xT,
                  __hip_bfloat16* __restrict__ Mt,
                  const __hip_bfloat16* __restrict__ E1cb,
                  const float* __restrict__ routeT,
                  float* __restrict__ outp)
{
    __shared__ __align__(16) char smem[81920];
    cg::grid_group grid = cg::this_grid();
    const int t = threadIdx.x;
    const int bid = blockIdx.x;
    const int wid = t >> 6, lane = t & 63;
    const int lo = lane & 15, hi = lane >> 4;

    // ======================= SECTION A (verbatim R12 phaseA) ================
    {
        const int L = bid;
        const int xc = L & 7, q = L >> 3;
        const int b = xc * 8 + (q >> 2);
        const int k0 = (q & 3) * 4;

        const char* e2p = (const char*)E2sb;
        const char* xp  = (const char*)(xT + (long)b * FF * NN);

        auto stage = [&](int buf, int c) {
            const int j0b = c * 128;
#pragma unroll
            for (int qq = 0; qq < 8; ++qq) {
                const int lbase = qq * 4096 + wid * 1024;
                const int Lb = lbase + lane * 16;
                const int r = Lb >> 7;
                const int cb = (Lb & 127) ^ ((r & 7) << 4);
                const int grow = (r >> 7) * 512 + (k0 + ((r >> 5) & 3)) * 32 + (r & 31);
                __builtin_amdgcn_global_load_lds(
                    (const __attribute__((address_space(1))) void*)(e2p + (long)grow * 1024 + j0b + cb),
                    (__attribute__((address_space(3))) void*)(smem + buf * 40960 + lbase),
                    16, 0, 0);
            }
#pragma unroll
            for (int g = 0; g < 2; ++g) {
                const int lbase = g * 4096 + wid * 1024;
                const int Lb = lbase + lane * 16;
                const int fr = Lb >> 7;
                const int cb = (Lb & 127) ^ ((fr & 7) << 4);
                __builtin_amdgcn_global_load_lds(
                    (const __attribute__((address_space(1))) void*)(xp + (long)fr * 1024 + j0b + cb),
                    (__attribute__((address_space(3))) void*)(smem + buf * 40960 + 32768 + lbase),
                    16, 0, 0);
            }
        };

        f32x4 acc[4][4] = {};
        int buf = 0;
        stage(0, 0);
        __syncthreads();

        for (int c = 0; c < 8; ++c) {
            if (c < 7) stage(buf ^ 1, c + 1);
            const char* base = smem + buf * 40960;
#pragma unroll
            for (int ks = 0; ks < 2; ++ks) {
                const int cbk = ks * 64 + hi * 16;
                bf16x8 a[4], bv[4];
#pragma unroll
                for (int am = 0; am < 4; ++am) {
                    const int ar = wid * 64 + am * 16 + lo;
                    a[am] = *(const bf16x8*)(base + ar * 128 + (cbk ^ ((ar & 7) << 4)));
                }
#pragma unroll
                for (int nf = 0; nf < 4; ++nf) {
                    const int fr = nf * 16 + lo;
                    bv[nf] = *(const bf16x8*)(base + 32768 + fr * 128 + (cbk ^ ((fr & 7) << 4)));
                }
#pragma unroll
                for (int am = 0; am < 4; ++am)
#pragma unroll
                    for (int nf = 0; nf < 4; ++nf)
                        acc[am][nf] = __builtin_amdgcn_mfma_f32_16x16x32_bf16(a[am], bv[nf], acc[am][nf], 0, 0, 0);
            }
            __syncthreads();
            buf ^= 1;
        }

        float* tl = (float*)smem;
#pragma unroll
        for (int am = 0; am < 4; ++am)
#pragma unroll
            for (int nf = 0; nf < 4; ++nf)
#pragma unroll
                for (int r = 0; r < 4; ++r)
                    tl[(wid * 64 + am * 16 + hi * 4 + r) * 65 + nf * 16 + lo] = acc[am][nf][r];
        __syncthreads();

        const int f = t >> 2, qd = t & 3;
        __hip_bfloat16* mb = Mt + (long)b * 65536 + (long)f * 1024;
#pragma unroll
        for (int g = 0; g < 8; ++g) {
            const int rbase = qd * 64 + g * 8;
            bf16x8 v;
#pragma unroll
            for (int j = 0; j < 8; ++j)
                v[j] = (__bf16)tl[(rbase + j) * 65 + f];
            const int e = rbase >> 7, kk = (rbase >> 5) & 3, d0 = rbase & 31;
            *(bf16x8*)(mb + (k0 + kk) * 64 + e * 32 + d0) = v;
        }
    }

    grid.sync();

    // ======================= SECTION B ======================================
    {
        const int xc = bid & 7, qq = bid >> 3;          // qq 0..31
        const int b = xc * 8 + (qq >> 2);
        const int i0 = (qq & 3) * 128;                  // 128 i-rows per block
        const int irow0 = i0 + wid * 32 + lo;           // isub=0 row
        // (isub=1 row = irow0 + 16)

        float wk[2][KK];
        const float* rT = routeT + (long)b * KK * NN + irow0;
#pragma unroll
        for (int k = 0; k < KK; ++k) {
            wk[0][k] = rT[k * NN];
            wk[1][k] = rT[k * NN + 16];
        }

        const char* mtp = (const char*)(Mt + (long)b * 65536);

        auto stageB = [&](int buf, int kk2) {
#pragma unroll
            for (int h = 0; h < 2; ++h) {
#pragma unroll
                for (int g = 0; g < 2; ++g) {
                    const int sbase = h * 8192 + wid * 2048 + g * 1024;  // wave-uniform
                    const int Lb = sbase + lane * 16;
                    const int ws_ = Lb & 8191;
                    const int fr = ws_ >> 7;
                    const int cb = (ws_ & 127) ^ ((fr & 7) << 4);
                    __builtin_amdgcn_global_load_lds(
                        (const __attribute__((address_space(1))) void*)(mtp + (long)fr * 2048 + (kk2 + h) * 128 + cb),
                        (__attribute__((address_space(3))) void*)(smem + buf * 16384 + sbase), 16, 0, 0);
                }
            }
        };

        f32x4 acc[2][4] = {};
        int buf = 0;
        stageB(0, 0);
        __syncthreads();

        for (int it = 0; it < 8; ++it) {
            const int kk2 = it * 2;
            if (it < 7) stageB(buf ^ 1, kk2 + 2);

            // A-frags for both kk and both isub (coalesced 1KB global reads)
            bf16x8 afr[2][2][2];                        // [isub][kkin][ks]
#pragma unroll
            for (int kkin = 0; kkin < 2; ++kkin) {
                const int kk = kk2 + kkin;
#pragma unroll
                for (int ks = 0; ks < 2; ++ks) {
#pragma unroll
                    for (int isub = 0; isub < 2; ++isub) {
                        const long off = ((long)(ks * KK + kk) * NN + irow0 + isub * 16) * GG + hi * 8;
                        bf16x8 v = *(const bf16x8*)(E1cb + off);
                        bf16x8 r;
#pragma unroll
                        for (int j = 0; j < 8; ++j)
                            r[j] = (__bf16)(wk[isub][kk] * (float)v[j]);
                        afr[isub][kkin][ks] = r;
                    }
                }
            }

#pragma unroll
            for (int kkin = 0; kkin < 2; ++kkin) {
#pragma unroll
                for (int ks = 0; ks < 2; ++ks) {
#pragma unroll
                    for (int nf = 0; nf < 4; ++nf) {
                        const int frow = nf * 16 + lo;
                        const int cb2 = (ks * 64 + hi * 16) ^ ((frow & 7) << 4);
                        bf16x8 bv = *(const bf16x8*)(smem + buf * 16384 + kkin * 8192 + frow * 128 + cb2);
                        acc[0][nf] = __builtin_amdgcn_mfma_f32_16x16x32_bf16(afr[0][kkin][ks], bv, acc[0][nf], 0, 0, 0);
                        acc[1][nf] = __builtin_amdgcn_mfma_f32_16x16x32_bf16(afr[1][kkin][ks], bv, acc[1][nf], 0, 0, 0);
                    }
                }
            }
            __syncthreads();
            buf ^= 1;
        }

#pragma unroll
        for (int isub = 0; isub < 2; ++isub) {
            float* og = outp + ((long)b * NN + i0 + wid * 32 + isub * 16) * FF;
#pragma unroll
            for (int nf = 0; nf < 4; ++nf)
#pragma unroll
                for (int r = 0; r < 4; ++r)
                    og[(hi * 4 + r) * FF + nf * 16 + lo] = acc[isub][nf][r];
        }
    }
}

// ---------------------------------------------------------------------------
extern "C" void kernel_launch(void* const* d_in, const int* in_sizes, int n_in,
                              void* d_out, int out_size, void* d_ws, size_t ws_size,
                              hipStream_t stream)
{
    const float* x   = (const float*)d_in[0];
    const float* E1  = (const float*)d_in[1];
    const float* E2  = (const float*)d_in[2];
    const float* rw  = (const float*)d_in[3];
    const float* rb  = (const float*)d_in[4];
    // d_in[5] = outer_lambda: algebraically unused (outer == identity)
    const float* lq1 = (const float*)d_in[6];
    const float* lk1 = (const float*)d_in[7];
    const float* lq2 = (const float*)d_in[8];
    const float* lk2 = (const float*)d_in[9];
    const int*  bias = (const int*)d_in[10];  // scalar shift: ordering-invariant

    float* ws    = (float*)d_ws;
    float* routeT = ws + ROUTET_OFF;
    __hip_bfloat16* E1cb = (__hip_bfloat16*)(ws + E1CB_OFF);
    __hip_bfloat16* E2sb = (__hip_bfloat16*)(ws + E2SB_OFF);
    __hip_bfloat16* xT   = (__hip_bfloat16*)(ws + XT_OFF);
    __hip_bfloat16* Mt   = (__hip_bfloat16*)(ws + MT_OFF);

    float* outp     = (float*)d_out;
    float* topk_out = outp + (long)BB * NN * FF;

    hipLaunchKernelGGL(prep_kernel, dim3(2304), dim3(256), 0, stream,
                       x, E1, E2, rw, rb, bias, lq1, lk1, lq2, lk2,
                       routeT, topk_out, E1cb, E2sb, xT);

    void* args[] = {
        (void*)&E2sb, (void*)&xT, (void*)&Mt, (void*)&E1cb,
        (void*)&routeT, (void*)&outp
    };
    hipLaunchCooperativeKernel((const void*)phaseAB_coop, dim3(256), dim3(256),
                               args, 0, stream);
}

// Round 14
// 46.593 us; speedup vs baseline: 1.8634x; 1.8634x over previous
//
#include <hip/hip_runtime.h>
#include <hip/hip_bf16.h>

#define BB 64
#define NN 512
#define FF 64
#define KK 16
#define GG 32
#define TOPKN 4

typedef __attribute__((ext_vector_type(8))) __bf16 bf16x8;
typedef __attribute__((ext_vector_type(4))) float f32x4;

// workspace layout (float offsets)
#define ROUTET_OFF 0                               // fp32 [b][k][i]  = 524288 f
#define E1CB_OFF   (BB*NN*KK)                      // bf16 [e,k,i,d]  = 262144 f
#define E2SB_OFF   (E1CB_OFF + (2*KK*NN*GG)/2)     // bf16 1024x512   = 262144 f
#define XT_OFF     (E2SB_OFF + (2*KK*GG*NN)/2)     // bf16 [b][f][j]  = 1048576 f
#define MT_OFF     (XT_OFF + (BB*FF*NN)/2)         // bf16 [b][f][ked]= 2097152 f

// ---------------------------------------------------------------------------
// Fused prep kernel, grid-sectioned (identical to R12)
// ---------------------------------------------------------------------------
__global__ __launch_bounds__(256)
void prep_kernel(const float* __restrict__ x, const float* __restrict__ E1,
                 const float* __restrict__ E2, const float* __restrict__ rw,
                 const float* __restrict__ rb, const int* __restrict__ bias,
                 const float* __restrict__ lq1, const float* __restrict__ lk1,
                 const float* __restrict__ lq2, const float* __restrict__ lk2,
                 float* __restrict__ routeT, float* __restrict__ topk_out,
                 __hip_bfloat16* __restrict__ E1cb,
                 __hip_bfloat16* __restrict__ E2sb,
                 __hip_bfloat16* __restrict__ xT)
{
    __shared__ float sm[4224];
    const int B = blockIdx.x;
    const int t = threadIdx.x;

    if (B < 512) {
        // ---- xpose ----
        const int b = B >> 3;
        const int j0 = (B & 7) * 64;
        const float* xb = x + (long)b * NN * FF;
        __hip_bfloat16* xo = xT + (long)b * FF * NN;
        const float4* src = (const float4*)(xb + (long)j0 * FF);
#pragma unroll
        for (int q = 0; q < 4; ++q) {
            int idx = t + q * 256;
            float4 v = src[idx];
            int j = idx >> 4;
            int f = (idx & 15) * 4;
            sm[j * 65 + f + 0] = v.x;
            sm[j * 65 + f + 1] = v.y;
            sm[j * 65 + f + 2] = v.z;
            sm[j * 65 + f + 3] = v.w;
        }
        __syncthreads();
#pragma unroll
        for (int q = 0; q < 16; ++q) {
            int idx = t + q * 256;
            int f = idx >> 6, j = idx & 63;
            xo[(long)f * NN + j0 + j] = __float2bfloat16(sm[j * 65 + f]);
        }
    } else if (B < 1536) {
        // ---- e2 softmax ----
        const long base = (long)(B - 512) * NN;
        float v0 = E2[base + t], v1 = E2[base + t + 256];
        float m = fmaxf(v0, v1);
#pragma unroll
        for (int s = 32; s >= 1; s >>= 1) m = fmaxf(m, __shfl_xor(m, s));
        if ((t & 63) == 0) sm[t >> 6] = m;
        __syncthreads();
        m = fmaxf(fmaxf(sm[0], sm[1]), fmaxf(sm[2], sm[3]));
        float e0 = expf(v0 - m), e1 = expf(v1 - m);
        float s2 = e0 + e1;
#pragma unroll
        for (int s = 32; s >= 1; s >>= 1) s2 += __shfl_xor(s2, s);
        __syncthreads();
        if ((t & 63) == 0) sm[t >> 6] = s2;
        __syncthreads();
        s2 = sm[0] + sm[1] + sm[2] + sm[3];
        E2sb[base + t] = __float2bfloat16(e0 / s2);
        E2sb[base + t + 256] = __float2bfloat16(e1 / s2);
    } else if (B < 2048) {
        // ---- e1 softmax * coef ----
        const long base = (long)(B - 1536) * 32;
        const int e = (int)(base >> 13);
        float coef = 1.0f;
        if (e) {
            float l1 = 0.f, l2 = 0.f;
#pragma unroll
            for (int i = 0; i < 64; ++i) {
                l1 = fmaf(lq1[i], lk1[i], l1);
                l2 = fmaf(lq2[i], lk2[i], l2);
            }
            const float lambda_init = 0.3555090675909692f;
            coef = -(expf(l1) - expf(l2) + lambda_init);
        }
        const int l = t & 31;
#pragma unroll
        for (int it = 0; it < 4; ++it) {
            const long row = base + it * 8 + (t >> 5);
            float val = E1[row * GG + l];
            float m = val;
#pragma unroll
            for (int s = 16; s >= 1; s >>= 1) m = fmaxf(m, __shfl_xor(m, s, 32));
            float ex = expf(val - m);
            float sum = ex;
#pragma unroll
            for (int s = 16; s >= 1; s >>= 1) sum += __shfl_xor(sum, s, 32);
            E1cb[row * GG + l] = __float2bfloat16(coef * (ex / sum));
        }
    } else {
        // ---- router: 2 half-threads per row; ordering by raw fp64 logit ----
        float* rwl = sm;
        float* rbl = sm + 1024;
        if (t < KK) rbl[t] = rb[t];
        for (int i = t; i < KK * FF; i += 256) rwl[i] = rw[i];
        __syncthreads();

        const int wv = t >> 6, ln = t & 63;
        const int khalf = ln >> 5;
        const long row = (long)(B - 2048) * 128 + wv * 32 + (ln & 31);

        float xr[FF];
        const float4* xrp = (const float4*)(x + row * FF);
#pragma unroll
        for (int c = 0; c < 16; ++c) {
            float4 v = xrp[c];
            xr[c * 4 + 0] = v.x; xr[c * 4 + 1] = v.y;
            xr[c * 4 + 2] = v.z; xr[c * 4 + 3] = v.w;
        }

        const int kb = khalf * 8;
        double mine[8];
#pragma unroll
        for (int kk = 0; kk < 8; ++kk) {
            double s = (double)rbl[kb + kk];
#pragma unroll
            for (int f = 0; f < FF; ++f)
                s += (double)rwl[(kb + kk) * FF + f] * (double)xr[f];
            mine[kk] = s;
        }
        double other[8];
#pragma unroll
        for (int i = 0; i < 8; ++i) other[i] = __shfl_xor(mine[i], 32);

        if (khalf == 0) {
            double sv[KK];
#pragma unroll
            for (int i = 0; i < 8; ++i) { sv[i] = mine[i]; sv[8 + i] = other[i]; }

            int idx4[TOPKN];
            double sval[TOPKN];
#pragma unroll
            for (int tt = 0; tt < TOPKN; ++tt) {
                double m = -1e300; int mi = 0;
#pragma unroll
                for (int k = 0; k < KK; ++k)
                    if (sv[k] > m) { m = sv[k]; mi = k; }
                idx4[tt] = mi;
                sval[tt] = m;
                sv[mi] = -1e300;
            }
            float sig4[TOPKN];
            float ssum = 0.f;
#pragma unroll
            for (int tt = 0; tt < TOPKN; ++tt) {
                sig4[tt] = 1.0f / (1.0f + expf(-(float)sval[tt]));
                ssum += sig4[tt];
            }
            float rv[KK];
#pragma unroll
            for (int k = 0; k < KK; ++k) rv[k] = 0.f;
#pragma unroll
            for (int tt = 0; tt < TOPKN; ++tt)
                rv[idx4[tt]] = sig4[tt] / ssum;

            const int b = (int)(row >> 9);
            const int n = (int)(row & 511);
#pragma unroll
            for (int k = 0; k < KK; ++k)
                routeT[((long)b * KK + k) * NN + n] = rv[k];
            float4 ti = make_float4((float)idx4[0], (float)idx4[1],
                                    (float)idx4[2], (float)idx4[3]);
            *(float4*)(topk_out + row * TOPKN) = ti;
        }
    }
}

// ---------------------------------------------------------------------------
// Kernel 4 (phase A, MFMA, 4x4 wave tile) — identical to R6/R10/R12.
// ---------------------------------------------------------------------------
__global__ __launch_bounds__(256, 2)
void phaseA_mfma(const __hip_bfloat16* __restrict__ E2sb,
                 const __hip_bfloat16* __restrict__ xT,
                 __hip_bfloat16* __restrict__ Mt)
{
    __shared__ __align__(16) char smem[81920];  // 2 x (A 32KB | B 8KB)
    const int t = threadIdx.x;
    const int L = blockIdx.x;
    const int xc = L & 7, q = L >> 3;           // q in [0,32)
    const int b = xc * 8 + (q >> 2);
    const int k0 = (q & 3) * 4;
    const int wid = t >> 6, lane = t & 63;
    const int lo = lane & 15, hi = lane >> 4;

    const char* e2p = (const char*)E2sb;
    const char* xp  = (const char*)(xT + (long)b * FF * NN);

    auto stage = [&](int buf, int c) {
        const int j0b = c * 128;    // byte offset within 1024B global row
        // A: 256 rows x 128B
#pragma unroll
        for (int qq = 0; qq < 8; ++qq) {
            const int lbase = qq * 4096 + wid * 1024;      // wave-uniform
            const int Lb = lbase + lane * 16;
            const int r = Lb >> 7;                          // 0..255
            const int cb = (Lb & 127) ^ ((r & 7) << 4);     // inverse swizzle
            const int grow = (r >> 7) * 512 + (k0 + ((r >> 5) & 3)) * 32 + (r & 31);
            __builtin_amdgcn_global_load_lds(
                (const __attribute__((address_space(1))) void*)(e2p + (long)grow * 1024 + j0b + cb),
                (__attribute__((address_space(3))) void*)(smem + buf * 40960 + lbase),
                16, 0, 0);
        }
        // B: 64 f rows x 128B
#pragma unroll
        for (int g = 0; g < 2; ++g) {
            const int lbase = g * 4096 + wid * 1024;        // within B region
            const int Lb = lbase + lane * 16;
            const int fr = Lb >> 7;                         // 0..63
            const int cb = (Lb & 127) ^ ((fr & 7) << 4);
            __builtin_amdgcn_global_load_lds(
                (const __attribute__((address_space(1))) void*)(xp + (long)fr * 1024 + j0b + cb),
                (__attribute__((address_space(3))) void*)(smem + buf * 40960 + 32768 + lbase),
                16, 0, 0);
        }
    };

    f32x4 acc[4][4] = {};
    int buf = 0;
    stage(0, 0);
    __syncthreads();

    for (int c = 0; c < 8; ++c) {
        if (c < 7) stage(buf ^ 1, c + 1);
        const char* base = smem + buf * 40960;
#pragma unroll
        for (int ks = 0; ks < 2; ++ks) {
            const int cbk = ks * 64 + hi * 16;
            bf16x8 a[4], bv[4];
#pragma unroll
            for (int am = 0; am < 4; ++am) {
                const int ar = wid * 64 + am * 16 + lo;
                a[am] = *(const bf16x8*)(base + ar * 128 + (cbk ^ ((ar & 7) << 4)));
            }
#pragma unroll
            for (int nf = 0; nf < 4; ++nf) {
                const int fr = nf * 16 + lo;
                bv[nf] = *(const bf16x8*)(base + 32768 + fr * 128 + (cbk ^ ((fr & 7) << 4)));
            }
#pragma unroll
            for (int am = 0; am < 4; ++am)
#pragma unroll
                for (int nf = 0; nf < 4; ++nf)
                    acc[am][nf] = __builtin_amdgcn_mfma_f32_16x16x32_bf16(a[am], bv[nf], acc[am][nf], 0, 0, 0);
        }
        __syncthreads();
        buf ^= 1;
    }

    // transpose via padded LDS [256 r][65] fp32 -> Mt bf16
    float* tl = (float*)smem;
#pragma unroll
    for (int am = 0; am < 4; ++am)
#pragma unroll
        for (int nf = 0; nf < 4; ++nf)
#pragma unroll
            for (int r = 0; r < 4; ++r)
                tl[(wid * 64 + am * 16 + hi * 4 + r) * 65 + nf * 16 + lo] = acc[am][nf][r];
    __syncthreads();

    const int f = t >> 2, qd = t & 3;
    __hip_bfloat16* mb = Mt + (long)b * 65536 + (long)f * 1024;
#pragma unroll
    for (int g = 0; g < 8; ++g) {
        const int rbase = qd * 64 + g * 8;
        bf16x8 v;
#pragma unroll
        for (int j = 0; j < 8; ++j)
            v[j] = (__bf16)tl[(rbase + j) * 65 + f];
        const int e = rbase >> 7, kk = (rbase >> 5) & 3, d0 = rbase & 31;
        *(bf16x8*)(mb + (k0 + kk) * 64 + e * 32 + d0) = v;
    }
}

// ---------------------------------------------------------------------------
// Kernel 5 (phase B, MFMA, isub-merged): 256 blocks x 128 i-rows.
// Each wave owns two 16-row sub-tiles (irow0, irow0+16) sharing ONE Mt
// staging stream: halves Mt L2 traffic, each staged ds_read feeds 2 MFMAs.
// (B math per output element identical to R12; validated inside R13.)
// ---------------------------------------------------------------------------
__global__ __launch_bounds__(256)
void phaseB_mfma(const __hip_bfloat16* __restrict__ Mt,
                 const __hip_bfloat16* __restrict__ E1cb,
                 const float* __restrict__ routeT,
                 float* __restrict__ outp)
{
    __shared__ __align__(16) char smem[32768];  // 2 bufs x (2 slices x 8KB)
    const int t = threadIdx.x;
    const int bid = blockIdx.x;
    const int xc = bid & 7, qq = bid >> 3;          // qq 0..31
    const int b = xc * 8 + (qq >> 2);
    const int i0 = (qq & 3) * 128;                  // 128 i-rows per block
    const int wid = t >> 6, lane = t & 63;
    const int lo = lane & 15, hi = lane >> 4;
    const int irow0 = i0 + wid * 32 + lo;           // isub=0 row (isub=1: +16)

    float wk[2][KK];
    const float* rT = routeT + (long)b * KK * NN + irow0;
#pragma unroll
    for (int k = 0; k < KK; ++k) {
        wk[0][k] = rT[k * NN];
        wk[1][k] = rT[k * NN + 16];
    }

    const char* mtp = (const char*)(Mt + (long)b * 65536);

    auto stageB = [&](int buf, int kk2) {
#pragma unroll
        for (int h = 0; h < 2; ++h) {
#pragma unroll
            for (int g = 0; g < 2; ++g) {
                const int sbase = h * 8192 + wid * 2048 + g * 1024;  // wave-uniform
                const int Lb = sbase + lane * 16;
                const int ws_ = Lb & 8191;
                const int fr = ws_ >> 7;
                const int cb = (ws_ & 127) ^ ((fr & 7) << 4);
                __builtin_amdgcn_global_load_lds(
                    (const __attribute__((address_space(1))) void*)(mtp + (long)fr * 2048 + (kk2 + h) * 128 + cb),
                    (__attribute__((address_space(3))) void*)(smem + buf * 16384 + sbase), 16, 0, 0);
            }
        }
    };

    f32x4 acc[2][4] = {};
    int buf = 0;
    stageB(0, 0);
    __syncthreads();

    for (int it = 0; it < 8; ++it) {
        const int kk2 = it * 2;
        if (it < 7) stageB(buf ^ 1, kk2 + 2);

        // A-frags for both kk and both isub (coalesced 1KB global reads)
        bf16x8 afr[2][2][2];                        // [isub][kkin][ks]
#pragma unroll
        for (int kkin = 0; kkin < 2; ++kkin) {
            const int kk = kk2 + kkin;
#pragma unroll
            for (int ks = 0; ks < 2; ++ks) {
#pragma unroll
                for (int isub = 0; isub < 2; ++isub) {
                    const long off = ((long)(ks * KK + kk) * NN + irow0 + isub * 16) * GG + hi * 8;
                    bf16x8 v = *(const bf16x8*)(E1cb + off);
                    bf16x8 r;
#pragma unroll
                    for (int j = 0; j < 8; ++j)
                        r[j] = (__bf16)(wk[isub][kk] * (float)v[j]);
                    afr[isub][kkin][ks] = r;
                }
            }
        }

#pragma unroll
        for (int kkin = 0; kkin < 2; ++kkin) {
#pragma unroll
            for (int ks = 0; ks < 2; ++ks) {
#pragma unroll
                for (int nf = 0; nf < 4; ++nf) {
                    const int frow = nf * 16 + lo;
                    const int cb2 = (ks * 64 + hi * 16) ^ ((frow & 7) << 4);
                    bf16x8 bv = *(const bf16x8*)(smem + buf * 16384 + kkin * 8192 + frow * 128 + cb2);
                    acc[0][nf] = __builtin_amdgcn_mfma_f32_16x16x32_bf16(afr[0][kkin][ks], bv, acc[0][nf], 0, 0, 0);
                    acc[1][nf] = __builtin_amdgcn_mfma_f32_16x16x32_bf16(afr[1][kkin][ks], bv, acc[1][nf], 0, 0, 0);
                }
            }
        }
        __syncthreads();
        buf ^= 1;
    }

#pragma unroll
    for (int isub = 0; isub < 2; ++isub) {
        float* og = outp + ((long)b * NN + i0 + wid * 32 + isub * 16) * FF;
#pragma unroll
        for (int nf = 0; nf < 4; ++nf)
#pragma unroll
            for (int r = 0; r < 4; ++r)
                og[(hi * 4 + r) * FF + nf * 16 + lo] = acc[isub][nf][r];
    }
}

// ---------------------------------------------------------------------------
extern "C" void kernel_launch(void* const* d_in, const int* in_sizes, int n_in,
                              void* d_out, int out_size, void* d_ws, size_t ws_size,
                              hipStream_t stream)
{
    const float* x   = (const float*)d_in[0];
    const float* E1  = (const float*)d_in[1];
    const float* E2  = (const float*)d_in[2];
    const float* rw  = (const float*)d_in[3];
    const float* rb  = (const float*)d_in[4];
    // d_in[5] = outer_lambda: algebraically unused (outer == identity)
    const float* lq1 = (const float*)d_in[6];
    const float* lk1 = (const float*)d_in[7];
    const float* lq2 = (const float*)d_in[8];
    const float* lk2 = (const float*)d_in[9];
    const int*  bias = (const int*)d_in[10];  // scalar shift: ordering-invariant

    float* ws    = (float*)d_ws;
    float* routeT = ws + ROUTET_OFF;
    __hip_bfloat16* E1cb = (__hip_bfloat16*)(ws + E1CB_OFF);
    __hip_bfloat16* E2sb = (__hip_bfloat16*)(ws + E2SB_OFF);
    __hip_bfloat16* xT   = (__hip_bfloat16*)(ws + XT_OFF);
    __hip_bfloat16* Mt   = (__hip_bfloat16*)(ws + MT_OFF);

    float* outp     = (float*)d_out;
    float* topk_out = outp + (long)BB * NN * FF;

    hipLaunchKernelGGL(prep_kernel, dim3(2304), dim3(256), 0, stream,
                       x, E1, E2, rw, rb, bias, lq1, lk1, lq2, lk2,
                       routeT, topk_out, E1cb, E2sb, xT);
    hipLaunchKernelGGL(phaseA_mfma, dim3(256), dim3(256), 0, stream,
                       E2sb, xT, Mt);
    hipLaunchKernelGGL(phaseB_mfma, dim3(256), dim3(256), 0, stream,
                       Mt, E1cb, routeT, outp);
}

// Round 15
// 42.252 us; speedup vs baseline: 2.0548x; 1.1027x over previous
//
#include <hip/hip_runtime.h>
#include <hip/hip_bf16.h>

#define BB 64
#define NN 512
#define FF 64
#define KK 16
#define GG 32
#define TOPKN 4

typedef __attribute__((ext_vector_type(8))) __bf16 bf16x8;
typedef __attribute__((ext_vector_type(4))) float f32x4;

// workspace layout (float offsets)
#define ROUTET_OFF 0                               // fp32 [b][k][i]  = 524288 f
#define E1CB_OFF   (BB*NN*KK)                      // bf16 [e,k,i,d]  = 262144 f
#define E2SB_OFF   (E1CB_OFF + (2*KK*NN*GG)/2)     // bf16 1024x512   = 262144 f
#define XT_OFF     (E2SB_OFF + (2*KK*GG*NN)/2)     // bf16 [b][f][j]  = 1048576 f
#define MT_OFF     (XT_OFF + (BB*FF*NN)/2)         // bf16 [b][f][ked]= 2097152 f

// ---------------------------------------------------------------------------
// Fused prep kernel, grid-sectioned:
//   [0,512):     xpose   x -> xT bf16 [b][f][j]
//   [512,1536):  e2 softmax -> E2sb bf16
//   [1536,2048): e1 softmax * coef -> E1cb bf16 (32 rows/block)
//   [2048,2304): router -> routeT + topk  (2 half-threads/row, no fp64 exp)
// ---------------------------------------------------------------------------
__global__ __launch_bounds__(256)
void prep_kernel(const float* __restrict__ x, const float* __restrict__ E1,
                 const float* __restrict__ E2, const float* __restrict__ rw,
                 const float* __restrict__ rb, const int* __restrict__ bias,
                 const float* __restrict__ lq1, const float* __restrict__ lk1,
                 const float* __restrict__ lq2, const float* __restrict__ lk2,
                 float* __restrict__ routeT, float* __restrict__ topk_out,
                 __hip_bfloat16* __restrict__ E1cb,
                 __hip_bfloat16* __restrict__ E2sb,
                 __hip_bfloat16* __restrict__ xT)
{
    __shared__ float sm[4224];
    const int B = blockIdx.x;
    const int t = threadIdx.x;

    if (B < 512) {
        // ---- xpose ----
        const int b = B >> 3;
        const int j0 = (B & 7) * 64;
        const float* xb = x + (long)b * NN * FF;
        __hip_bfloat16* xo = xT + (long)b * FF * NN;
        const float4* src = (const float4*)(xb + (long)j0 * FF);
#pragma unroll
        for (int q = 0; q < 4; ++q) {
            int idx = t + q * 256;
            float4 v = src[idx];
            int j = idx >> 4;
            int f = (idx & 15) * 4;
            sm[j * 65 + f + 0] = v.x;
            sm[j * 65 + f + 1] = v.y;
            sm[j * 65 + f + 2] = v.z;
            sm[j * 65 + f + 3] = v.w;
        }
        __syncthreads();
#pragma unroll
        for (int q = 0; q < 16; ++q) {
            int idx = t + q * 256;
            int f = idx >> 6, j = idx & 63;
            xo[(long)f * NN + j0 + j] = __float2bfloat16(sm[j * 65 + f]);
        }
    } else if (B < 1536) {
        // ---- e2 softmax ----
        const long base = (long)(B - 512) * NN;
        float v0 = E2[base + t], v1 = E2[base + t + 256];
        float m = fmaxf(v0, v1);
#pragma unroll
        for (int s = 32; s >= 1; s >>= 1) m = fmaxf(m, __shfl_xor(m, s));
        if ((t & 63) == 0) sm[t >> 6] = m;
        __syncthreads();
        m = fmaxf(fmaxf(sm[0], sm[1]), fmaxf(sm[2], sm[3]));
        float e0 = expf(v0 - m), e1 = expf(v1 - m);
        float s2 = e0 + e1;
#pragma unroll
        for (int s = 32; s >= 1; s >>= 1) s2 += __shfl_xor(s2, s);
        __syncthreads();
        if ((t & 63) == 0) sm[t >> 6] = s2;
        __syncthreads();
        s2 = sm[0] + sm[1] + sm[2] + sm[3];
        E2sb[base + t] = __float2bfloat16(e0 / s2);
        E2sb[base + t + 256] = __float2bfloat16(e1 / s2);
    } else if (B < 2048) {
        // ---- e1 softmax * coef ----
        const long base = (long)(B - 1536) * 32;
        const int e = (int)(base >> 13);
        float coef = 1.0f;
        if (e) {
            float l1 = 0.f, l2 = 0.f;
#pragma unroll
            for (int i = 0; i < 64; ++i) {
                l1 = fmaf(lq1[i], lk1[i], l1);
                l2 = fmaf(lq2[i], lk2[i], l2);
            }
            const float lambda_init = 0.3555090675909692f;
            coef = -(expf(l1) - expf(l2) + lambda_init);
        }
        const int l = t & 31;
#pragma unroll
        for (int it = 0; it < 4; ++it) {
            const long row = base + it * 8 + (t >> 5);
            float val = E1[row * GG + l];
            float m = val;
#pragma unroll
            for (int s = 16; s >= 1; s >>= 1) m = fmaxf(m, __shfl_xor(m, s, 32));
            float ex = expf(val - m);
            float sum = ex;
#pragma unroll
            for (int s = 16; s >= 1; s >>= 1) sum += __shfl_xor(sum, s, 32);
            E1cb[row * GG + l] = __float2bfloat16(coef * (ex / sum));
        }
    } else {
        // ---- router: 2 half-threads per row; ordering by raw fp64 logit ----
        float* rwl = sm;
        float* rbl = sm + 1024;
        if (t < KK) rbl[t] = rb[t];
        for (int i = t; i < KK * FF; i += 256) rwl[i] = rw[i];
        __syncthreads();

        const int wv = t >> 6, ln = t & 63;
        const int khalf = ln >> 5;
        const long row = (long)(B - 2048) * 128 + wv * 32 + (ln & 31);

        float xr[FF];
        const float4* xrp = (const float4*)(x + row * FF);
#pragma unroll
        for (int c = 0; c < 16; ++c) {
            float4 v = xrp[c];
            xr[c * 4 + 0] = v.x; xr[c * 4 + 1] = v.y;
            xr[c * 4 + 2] = v.z; xr[c * 4 + 3] = v.w;
        }

        const int kb = khalf * 8;
        double mine[8];
#pragma unroll
        for (int kk = 0; kk < 8; ++kk) {
            double s = (double)rbl[kb + kk];
#pragma unroll
            for (int f = 0; f < FF; ++f)
                s += (double)rwl[(kb + kk) * FF + f] * (double)xr[f];
            mine[kk] = s;
        }
        double other[8];
#pragma unroll
        for (int i = 0; i < 8; ++i) other[i] = __shfl_xor(mine[i], 32);

        if (khalf == 0) {
            double sv[KK];
#pragma unroll
            for (int i = 0; i < 8; ++i) { sv[i] = mine[i]; sv[8 + i] = other[i]; }

            int idx4[TOPKN];
            double sval[TOPKN];
#pragma unroll
            for (int tt = 0; tt < TOPKN; ++tt) {
                double m = -1e300; int mi = 0;
#pragma unroll
                for (int k = 0; k < KK; ++k)
                    if (sv[k] > m) { m = sv[k]; mi = k; }
                idx4[tt] = mi;
                sval[tt] = m;
                sv[mi] = -1e300;
            }
            float sig4[TOPKN];
            float ssum = 0.f;
#pragma unroll
            for (int tt = 0; tt < TOPKN; ++tt) {
                sig4[tt] = 1.0f / (1.0f + expf(-(float)sval[tt]));
                ssum += sig4[tt];
            }
            float rv[KK];
#pragma unroll
            for (int k = 0; k < KK; ++k) rv[k] = 0.f;
#pragma unroll
            for (int tt = 0; tt < TOPKN; ++tt)
                rv[idx4[tt]] = sig4[tt] / ssum;

            const int b = (int)(row >> 9);
            const int n = (int)(row & 511);
#pragma unroll
            for (int k = 0; k < KK; ++k)
                routeT[((long)b * KK + k) * NN + n] = rv[k];
            float4 ti = make_float4((float)idx4[0], (float)idx4[1],
                                    (float)idx4[2], (float)idx4[3]);
            *(float4*)(topk_out + row * TOPKN) = ti;
        }
    }
}

// ---------------------------------------------------------------------------
// Kernel 4 (phase A, MFMA, 4x4 wave tile): grid 256 = (b, kg of 4 k's).
// Per block: A[256 r][512 j] (r=(e,kk,d)) x B=xT[64 f][512 j] -> 256x64.
// K-chunks of 64; dbuf 2x40KB LDS; 2-phase pipeline, 1 barrier/chunk.
// 2 blocks/CU (proven best). Epilogue: padded-LDS transpose -> Mt bf16.
// ---------------------------------------------------------------------------
__global__ __launch_bounds__(256, 2)
void phaseA_mfma(const __hip_bfloat16* __restrict__ E2sb,
                 const __hip_bfloat16* __restrict__ xT,
                 __hip_bfloat16* __restrict__ Mt)
{
    __shared__ __align__(16) char smem[81920];  // 2 x (A 32KB | B 8KB)
    const int t = threadIdx.x;
    const int L = blockIdx.x;
    const int xc = L & 7, q = L >> 3;           // q in [0,32)
    const int b = xc * 8 + (q >> 2);
    const int k0 = (q & 3) * 4;
    const int wid = t >> 6, lane = t & 63;
    const int lo = lane & 15, hi = lane >> 4;

    const char* e2p = (const char*)E2sb;
    const char* xp  = (const char*)(xT + (long)b * FF * NN);

    auto stage = [&](int buf, int c) {
        const int j0b = c * 128;    // byte offset within 1024B global row
        // A: 256 rows x 128B
#pragma unroll
        for (int qq = 0; qq < 8; ++qq) {
            const int lbase = qq * 4096 + wid * 1024;      // wave-uniform
            const int Lb = lbase + lane * 16;
            const int r = Lb >> 7;                          // 0..255
            const int cb = (Lb & 127) ^ ((r & 7) << 4);     // inverse swizzle
            const int grow = (r >> 7) * 512 + (k0 + ((r >> 5) & 3)) * 32 + (r & 31);
            __builtin_amdgcn_global_load_lds(
                (const __attribute__((address_space(1))) void*)(e2p + (long)grow * 1024 + j0b + cb),
                (__attribute__((address_space(3))) void*)(smem + buf * 40960 + lbase),
                16, 0, 0);
        }
        // B: 64 f rows x 128B
#pragma unroll
        for (int g = 0; g < 2; ++g) {
            const int lbase = g * 4096 + wid * 1024;        // within B region
            const int Lb = lbase + lane * 16;
            const int fr = Lb >> 7;                         // 0..63
            const int cb = (Lb & 127) ^ ((fr & 7) << 4);
            __builtin_amdgcn_global_load_lds(
                (const __attribute__((address_space(1))) void*)(xp + (long)fr * 1024 + j0b + cb),
                (__attribute__((address_space(3))) void*)(smem + buf * 40960 + 32768 + lbase),
                16, 0, 0);
        }
    };

    f32x4 acc[4][4] = {};
    int buf = 0;
    stage(0, 0);
    __syncthreads();

    for (int c = 0; c < 8; ++c) {
        if (c < 7) stage(buf ^ 1, c + 1);
        const char* base = smem + buf * 40960;
#pragma unroll
        for (int ks = 0; ks < 2; ++ks) {
            const int cbk = ks * 64 + hi * 16;
            bf16x8 a[4], bv[4];
#pragma unroll
            for (int am = 0; am < 4; ++am) {
                const int ar = wid * 64 + am * 16 + lo;
                a[am] = *(const bf16x8*)(base + ar * 128 + (cbk ^ ((ar & 7) << 4)));
            }
#pragma unroll
            for (int nf = 0; nf < 4; ++nf) {
                const int fr = nf * 16 + lo;
                bv[nf] = *(const bf16x8*)(base + 32768 + fr * 128 + (cbk ^ ((fr & 7) << 4)));
            }
#pragma unroll
            for (int am = 0; am < 4; ++am)
#pragma unroll
                for (int nf = 0; nf < 4; ++nf)
                    acc[am][nf] = __builtin_amdgcn_mfma_f32_16x16x32_bf16(a[am], bv[nf], acc[am][nf], 0, 0, 0);
        }
        __syncthreads();
        buf ^= 1;
    }

    // transpose via padded LDS [256 r][65] fp32 -> Mt bf16
    float* tl = (float*)smem;
#pragma unroll
    for (int am = 0; am < 4; ++am)
#pragma unroll
        for (int nf = 0; nf < 4; ++nf)
#pragma unroll
            for (int r = 0; r < 4; ++r)
                tl[(wid * 64 + am * 16 + hi * 4 + r) * 65 + nf * 16 + lo] = acc[am][nf][r];
    __syncthreads();

    const int f = t >> 2, qd = t & 3;
    __hip_bfloat16* mb = Mt + (long)b * 65536 + (long)f * 1024;
#pragma unroll
    for (int g = 0; g < 8; ++g) {
        const int rbase = qd * 64 + g * 8;
        bf16x8 v;
#pragma unroll
        for (int j = 0; j < 8; ++j)
            v[j] = (__bf16)tl[(rbase + j) * 65 + f];
        const int e = rbase >> 7, kk = (rbase >> 5) & 3, d0 = rbase & 31;
        *(bf16x8*)(mb + (k0 + kk) * 64 + e * 32 + d0) = v;
    }
}

// ---------------------------------------------------------------------------
// Kernel 5 (phase B, MFMA): per b: out[512 x 64] = W[512 x 1024] @ Mt^T
// W built on the fly: A-frag = E1cb segment * route weight (registers only).
// 512 blocks (2/CU — proven best), kk-PAIR staging, dbuf 2x16KB.
// ---------------------------------------------------------------------------
__global__ __launch_bounds__(256)
void phaseB_mfma(const __hip_bfloat16* __restrict__ Mt,
                 const __hip_bfloat16* __restrict__ E1cb,
                 const float* __restrict__ routeT,
                 float* __restrict__ out)
{
    __shared__ __align__(16) char smem[32768];  // 2 bufs x (2 slices x 8KB)
    const int t = threadIdx.x;
    const int L = blockIdx.x;
    const int xc = L & 7, q = L >> 3;
    const int b = xc * 8 + (q >> 3);
    const int i0 = (q & 7) * 64;
    const int wid = t >> 6, lane = t & 63;
    const int lo = lane & 15, hi = lane >> 4;
    const int irow = i0 + wid * 16 + lo;

    float wk[KK];
    const float* rT = routeT + (long)b * KK * NN + irow;
#pragma unroll
    for (int k = 0; k < KK; ++k) wk[k] = rT[k * NN];

    const char* mtp = (const char*)(Mt + (long)b * 65536);

    auto stageB = [&](int buf, int kk2) {
#pragma unroll
        for (int h = 0; h < 2; ++h) {
#pragma unroll
            for (int g = 0; g < 2; ++g) {
                const int sbase = h * 8192 + wid * 2048 + g * 1024;  // wave-uniform
                const int Lb = sbase + lane * 16;
                const int ws_ = Lb & 8191;
                const int fr = ws_ >> 7;
                const int cb = (ws_ & 127) ^ ((fr & 7) << 4);
                __builtin_amdgcn_global_load_lds(
                    (const __attribute__((address_space(1))) void*)(mtp + (long)fr * 2048 + (kk2 + h) * 128 + cb),
                    (__attribute__((address_space(3))) void*)(smem + buf * 16384 + sbase), 16, 0, 0);
            }
        }
    };

    f32x4 acc[4] = {};
    int buf = 0;
    stageB(0, 0);
    __syncthreads();

    for (int it = 0; it < 8; ++it) {
        const int kk2 = it * 2;
        if (it < 7) stageB(buf ^ 1, kk2 + 2);

        bf16x8 afr[2][2];
#pragma unroll
        for (int kkin = 0; kkin < 2; ++kkin) {
            const int kk = kk2 + kkin;
#pragma unroll
            for (int ks = 0; ks < 2; ++ks) {
                const long off = ((long)(ks * KK + kk) * NN + irow) * GG + hi * 8;
                bf16x8 v = *(const bf16x8*)(E1cb + off);
                bf16x8 r;
#pragma unroll
                for (int j = 0; j < 8; ++j)
                    r[j] = (__bf16)(wk[kk] * (float)v[j]);
                afr[kkin][ks] = r;
            }
        }

#pragma unroll
        for (int kkin = 0; kkin < 2; ++kkin) {
#pragma unroll
            for (int ks = 0; ks < 2; ++ks) {
#pragma unroll
                for (int nf = 0; nf < 4; ++nf) {
                    const int frow = nf * 16 + lo;
                    const int cb2 = (ks * 64 + hi * 16) ^ ((frow & 7) << 4);
                    bf16x8 bv = *(const bf16x8*)(smem + buf * 16384 + kkin * 8192 + frow * 128 + cb2);
                    acc[nf] = __builtin_amdgcn_mfma_f32_16x16x32_bf16(afr[kkin][ks], bv, acc[nf], 0, 0, 0);
                }
            }
        }
        __syncthreads();
        buf ^= 1;
    }

    float* og = out + ((long)b * NN + i0 + wid * 16) * FF;
#pragma unroll
    for (int nf = 0; nf < 4; ++nf)
#pragma unroll
        for (int r = 0; r < 4; ++r)
            og[(hi * 4 + r) * FF + nf * 16 + lo] = acc[nf][r];
}

// ---------------------------------------------------------------------------
extern "C" void kernel_launch(void* const* d_in, const int* in_sizes, int n_in,
                              void* d_out, int out_size, void* d_ws, size_t ws_size,
                              hipStream_t stream)
{
    const float* x   = (const float*)d_in[0];
    const float* E1  = (const float*)d_in[1];
    const float* E2  = (const float*)d_in[2];
    const float* rw  = (const float*)d_in[3];
    const float* rb  = (const float*)d_in[4];
    // d_in[5] = outer_lambda: algebraically unused (outer == identity)
    const float* lq1 = (const float*)d_in[6];
    const float* lk1 = (const float*)d_in[7];
    const float* lq2 = (const float*)d_in[8];
    const float* lk2 = (const float*)d_in[9];
    const int*  bias = (const int*)d_in[10];  // scalar shift: ordering-invariant

    float* ws    = (float*)d_ws;
    float* routeT = ws + ROUTET_OFF;
    __hip_bfloat16* E1cb = (__hip_bfloat16*)(ws + E1CB_OFF);
    __hip_bfloat16* E2sb = (__hip_bfloat16*)(ws + E2SB_OFF);
    __hip_bfloat16* xT   = (__hip_bfloat16*)(ws + XT_OFF);
    __hip_bfloat16* Mt   = (__hip_bfloat16*)(ws + MT_OFF);

    float* out      = (float*)d_out;
    float* topk_out = out + (long)BB * NN * FF;

    hipLaunchKernelGGL(prep_kernel, dim3(2304), dim3(256), 0, stream,
                       x, E1, E2, rw, rb, bias, lq1, lk1, lq2, lk2,
                       routeT, topk_out, E1cb, E2sb, xT);
    hipLaunchKernelGGL(phaseA_mfma, dim3(256), dim3(256), 0, stream,
                       E2sb, xT, Mt);
    hipLaunchKernelGGL(phaseB_mfma, dim3(512), dim3(256), 0, stream,
                       Mt, E1cb, routeT, out);
}